// Round 1
// baseline (321.271 us; speedup 1.0000x reference)
//
#include <hip/hip_runtime.h>

#define H_    200
#define W_    200
#define C_    256
#define NROI  4096
#define KDIM  12544   // 49*256
#define HID_  256
#define NCLS_ 21

typedef __bf16 bf16x8 __attribute__((ext_vector_type(8)));
typedef float  f32x4  __attribute__((ext_vector_type(4)));

__device__ __forceinline__ unsigned short f2bf(float f) {
  unsigned u = __float_as_uint(f);
  return (unsigned short)((u + 0x7FFFu + ((u >> 16) & 1u)) >> 16);  // RNE, no NaN inputs
}
__device__ __forceinline__ float bf2f(unsigned short u) {
  return __uint_as_float(((unsigned)u) << 16);
}
__device__ __forceinline__ void gload16(const void* g, void* l) {
  __builtin_amdgcn_global_load_lds((const __attribute__((address_space(1))) unsigned int*)g,
                                   (__attribute__((address_space(3))) unsigned int*)l, 16, 0, 0);
}

// ---------------- features f32 -> bf16 ----------------
__global__ __launch_bounds__(256) void cvt_features(const float* __restrict__ F,
                                                    unsigned short* __restrict__ Fb) {
  const int n4 = (H_ * W_ * C_) / 4;
  for (int i = blockIdx.x * 256 + threadIdx.x; i < n4; i += gridDim.x * 256) {
    float4 v = ((const float4*)F)[i];
    ushort4 o;
    o.x = f2bf(v.x); o.y = f2bf(v.y); o.z = f2bf(v.z); o.w = f2bf(v.w);
    ((ushort4*)Fb)[i] = o;
  }
}

// ---------------- W1 (K x N) f32 -> BT (N x K) bf16 ----------------
__global__ __launch_bounds__(256) void transpose_w1(const float* __restrict__ W1,
                                                    unsigned short* __restrict__ BT) {
  __shared__ float tile[32][33];
  const int k0 = blockIdx.x * 32;   // 392
  const int n0 = blockIdx.y * 32;   // 8
  const int tx = threadIdx.x & 31;
  const int ty = threadIdx.x >> 5;  // 0..7
#pragma unroll
  for (int i = 0; i < 4; ++i)
    tile[ty + 8 * i][tx] = W1[(size_t)(k0 + ty + 8 * i) * HID_ + n0 + tx];
  __syncthreads();
#pragma unroll
  for (int i = 0; i < 4; ++i) {
    const int n = ty + 8 * i;
    BT[(size_t)(n0 + n) * KDIM + k0 + tx] = f2bf(tile[tx][n]);
  }
}

// ---------------- ROI max pool: X (NROI x KDIM) bf16 ----------------
__global__ __launch_bounds__(256) void roi_pool(const unsigned short* __restrict__ Fb,
                                                const float* __restrict__ rois,
                                                unsigned short* __restrict__ X) {
  const int task = blockIdx.x * 4 + (threadIdx.x >> 6);  // (roi, cell)
  const int lane = threadIdx.x & 63;
  const int roi  = task / 49;
  const int cell = task - roi * 49;
  const int py = cell / 7;
  const int px = cell - py * 7;

  float4 r = ((const float4*)rois)[roi];
  const float y1 = fminf(r.x, r.z), y2 = fmaxf(r.x, r.z);
  const float x1 = fminf(r.y, r.w), x2 = fmaxf(r.y, r.w);
  const float dy = __fsub_rn(y2, y1), dx = __fsub_rn(x2, x1);

  int iy[2], ix[2];
#pragma unroll
  for (int g = 0; g < 2; ++g) {
    // t = (s + 0.5)/14 in f32, ys = y1 + dy*t (separate mul/add, RNE), idx = rint(ys*199)
    float tyv = __fdiv_rn(__fadd_rn((float)(2 * py + g), 0.5f), 14.0f);
    float txv = __fdiv_rn(__fadd_rn((float)(2 * px + g), 0.5f), 14.0f);
    float ys = __fadd_rn(y1, __fmul_rn(dy, tyv));
    float xs = __fadd_rn(x1, __fmul_rn(dx, txv));
    int yi = (int)rintf(__fmul_rn(ys, 199.0f));
    int xi = (int)rintf(__fmul_rn(xs, 199.0f));
    iy[g] = min(max(yi, 0), H_ - 1);
    ix[g] = min(max(xi, 0), W_ - 1);
  }

  const ushort4* p00 = (const ushort4*)(Fb + ((size_t)(iy[0] * W_ + ix[0])) * C_);
  const ushort4* p01 = (const ushort4*)(Fb + ((size_t)(iy[0] * W_ + ix[1])) * C_);
  const ushort4* p10 = (const ushort4*)(Fb + ((size_t)(iy[1] * W_ + ix[0])) * C_);
  const ushort4* p11 = (const ushort4*)(Fb + ((size_t)(iy[1] * W_ + ix[1])) * C_);
  ushort4 a = p00[lane], b = p01[lane], c = p10[lane], d = p11[lane];
  ushort4 o;
  {
    float m0 = fmaxf(fmaxf(bf2f(a.x), bf2f(b.x)), fmaxf(bf2f(c.x), bf2f(d.x)));
    float m1 = fmaxf(fmaxf(bf2f(a.y), bf2f(b.y)), fmaxf(bf2f(c.y), bf2f(d.y)));
    float m2 = fmaxf(fmaxf(bf2f(a.z), bf2f(b.z)), fmaxf(bf2f(c.z), bf2f(d.z)));
    float m3 = fmaxf(fmaxf(bf2f(a.w), bf2f(b.w)), fmaxf(bf2f(c.w), bf2f(d.w)));
    o.x = (unsigned short)(__float_as_uint(m0) >> 16);  // exact: max of bf16 values
    o.y = (unsigned short)(__float_as_uint(m1) >> 16);
    o.z = (unsigned short)(__float_as_uint(m2) >> 16);
    o.w = (unsigned short)(__float_as_uint(m3) >> 16);
  }
  ((ushort4*)(X + (size_t)roi * KDIM + cell * 256))[lane] = o;
}

// ---------------- GEMM: Hh = relu(X @ W1 + b1), bf16 MFMA ----------------
#define BM 64
#define BN 32
#define BK 64
#define NT (KDIM / BK)   // 196

__global__ __launch_bounds__(256) void gemm_h(const unsigned short* __restrict__ X,
                                              const unsigned short* __restrict__ BT,
                                              const float* __restrict__ bias1,
                                              float* __restrict__ Hh) {
  __shared__ __align__(16) unsigned char As[2][BM * 128];  // 64 rows x 128B (swizzled layout)
  __shared__ __align__(16) unsigned char Bs[2][BN * 128];  // 32 rows x 128B
  const int tid  = threadIdx.x;
  const int lane = tid & 63;
  const int w    = tid >> 6;             // wave 0..3, wave w owns output rows [w*16, w*16+16)
  const int bm   = blockIdx.x >> 3;      // 64
  const int bn   = blockIdx.x & 7;       // 8

  // --- staging: linear LDS dest (base + lane*16), inverse-swizzled global source ---
  const int srow  = lane >> 3;                          // row-within-8 this lane stages
  const int sbyte = ((lane & 7) << 4) ^ (srow << 4);    // XOR-preswizzled byte-in-row
  const unsigned short* gA0 = X  + (size_t)(bm * BM + w * 16 + srow) * KDIM + (sbyte >> 1);
  const unsigned short* gA1 = gA0 + (size_t)8 * KDIM;
  const unsigned short* gB0 = BT + (size_t)(bn * BN + w * 8 + srow) * KDIM + (sbyte >> 1);
  unsigned char* ldsA0[2] = { &As[0][(w * 16) * 128],     &As[1][(w * 16) * 128] };
  unsigned char* ldsA1[2] = { &As[0][(w * 16 + 8) * 128], &As[1][(w * 16 + 8) * 128] };
  unsigned char* ldsB0[2] = { &Bs[0][(w * 8) * 128],      &Bs[1][(w * 8) * 128] };

  // --- LDS fragment-read offsets (swizzled), precomputed ---
  const int arow  = w * 16 + (lane & 15);
  const int kbyte = (lane >> 4) << 4;    // k-group * 16B
  int aoff[2], boff[2][2];
#pragma unroll
  for (int kf = 0; kf < 2; ++kf) {
    const int kb = kf * 64 + kbyte;
    aoff[kf] = arow * 128 + (kb ^ ((arow & 7) << 4));
#pragma unroll
    for (int n = 0; n < 2; ++n) {
      const int brow = n * 16 + (lane & 15);
      boff[kf][n] = brow * 128 + (kb ^ ((brow & 7) << 4));
    }
  }

  f32x4 acc[2] = {};

  // prologue: stage tile 0
  gload16(gA0, ldsA0[0]);
  gload16(gA1, ldsA1[0]);
  gload16(gB0, ldsB0[0]);

  for (int t = 0; t < NT; ++t) {
    const int cur = t & 1;
    __syncthreads();                       // drains vmcnt -> tile `cur` ready; prev reads done
    if (t + 1 < NT) {                      // prefetch next tile into other buffer
      const int nx = cur ^ 1;
      const size_t koff = (size_t)(t + 1) * BK;
      gload16(gA0 + koff, ldsA0[nx]);
      gload16(gA1 + koff, ldsA1[nx]);
      gload16(gB0 + koff, ldsB0[nx]);
    }
    const unsigned char* Ab = As[cur];
    const unsigned char* Bb = Bs[cur];
#pragma unroll
    for (int kf = 0; kf < 2; ++kf) {
      bf16x8 af  = *(const bf16x8*)(Ab + aoff[kf]);
      bf16x8 bf0 = *(const bf16x8*)(Bb + boff[kf][0]);
      bf16x8 bf1 = *(const bf16x8*)(Bb + boff[kf][1]);
      acc[0] = __builtin_amdgcn_mfma_f32_16x16x32_bf16(af, bf0, acc[0], 0, 0, 0);
      acc[1] = __builtin_amdgcn_mfma_f32_16x16x32_bf16(af, bf1, acc[1], 0, 0, 0);
    }
  }

  // epilogue: D[row][col], row=(lane>>4)*4+j, col=lane&15
  const int orow = bm * BM + w * 16 + ((lane >> 4) << 2);
#pragma unroll
  for (int n = 0; n < 2; ++n) {
    const int col = bn * BN + n * 16 + (lane & 15);
    const float bv = bias1[col];
#pragma unroll
    for (int j = 0; j < 4; ++j) {
      float v = acc[n][j] + bv;
      Hh[(size_t)(orow + j) * HID_ + col] = v > 0.f ? v : 0.f;
    }
  }
}

// ---------------- heads: logits (NROI x 21), bbox (NROI x 84) ----------------
__global__ __launch_bounds__(256) void heads_k(const float* __restrict__ Hh,
                                               const float* __restrict__ Wc,
                                               const float* __restrict__ bc,
                                               const float* __restrict__ Wb,
                                               const float* __restrict__ bb,
                                               float* __restrict__ logits,
                                               float* __restrict__ bbox) {
  const int t = threadIdx.x;
  const int roi = blockIdx.x * 2 + (t >> 7);
  const int o = t & 127;
  if (o >= 105) return;
  const float* h = Hh + (size_t)roi * HID_;
  const float* wp;
  int stride;
  float acc;
  if (o < 21) { wp = Wc + o;        stride = NCLS_;     acc = bc[o]; }
  else        { wp = Wb + (o - 21); stride = NCLS_ * 4; acc = bb[o - 21]; }
#pragma unroll 8
  for (int k = 0; k < HID_; ++k) acc = fmaf(h[k], wp[(size_t)k * stride], acc);
  if (o < 21) logits[(size_t)roi * NCLS_ + o] = acc;
  else        bbox[(size_t)roi * 84 + (o - 21)] = acc;
}

// ---------------- per-ROI loss + reduction ----------------
__global__ __launch_bounds__(256) void loss_k(const float* __restrict__ logits,
                                              const float* __restrict__ bbox,
                                              const int* __restrict__ labels,
                                              const float* __restrict__ tgt,
                                              float* __restrict__ out) {
  const int roi = blockIdx.x * 256 + threadIdx.x;
  const float* lg = logits + (size_t)roi * NCLS_;
  float m = lg[0];
#pragma unroll
  for (int i = 1; i < NCLS_; ++i) m = fmaxf(m, lg[i]);
  float s = 0.f;
#pragma unroll
  for (int i = 0; i < NCLS_; ++i) s += expf(lg[i] - m);
  const float lse = m + logf(s);
  const int lab = labels[roi];
  float contrib = lse - lg[lab];          // -logp[label]
#pragma unroll
  for (int j = 0; j < 4; ++j) {
    float d = bbox[(size_t)roi * 84 + lab * 4 + j] - tgt[roi * 4 + j];
    float ad = fabsf(d);
    contrib += (ad < 1.f) ? 0.5f * d * d : ad - 0.5f;
  }
  contrib *= (1.0f / NROI);
#pragma unroll
  for (int off = 32; off > 0; off >>= 1) contrib += __shfl_down(contrib, off);
  __shared__ float wsum[4];
  const int lane = threadIdx.x & 63, wv = threadIdx.x >> 6;
  if (lane == 0) wsum[wv] = contrib;
  __syncthreads();
  if (threadIdx.x == 0) atomicAdd(out, wsum[0] + wsum[1] + wsum[2] + wsum[3]);
}

extern "C" void kernel_launch(void* const* d_in, const int* in_sizes, int n_in,
                              void* d_out, int out_size, void* d_ws, size_t ws_size,
                              hipStream_t stream) {
  const float* features = (const float*)d_in[0];
  const float* rois     = (const float*)d_in[1];
  const int*   labels   = (const int*)d_in[2];
  const float* tgt      = (const float*)d_in[3];
  const float* W1       = (const float*)d_in[4];
  const float* b1       = (const float*)d_in[5];
  const float* Wc       = (const float*)d_in[6];
  const float* bc       = (const float*)d_in[7];
  const float* Wb       = (const float*)d_in[8];
  const float* bb       = (const float*)d_in[9];

  char* ws = (char*)d_ws;
  unsigned short* X      = (unsigned short*)(ws);                 // 4096*12544 bf16
  unsigned short* BTm    = (unsigned short*)(ws + 102760448);     // 256*12544 bf16
  float*          Hh     = (float*)(ws + 109182976);              // 4096*256 f32
  float*          logits = (float*)(ws + 113377280);              // 4096*21
  float*          bbox   = (float*)(ws + 113721344);              // 4096*84
  unsigned short* Fb     = (unsigned short*)(ws + 115097600);     // 200*200*256 bf16

  hipMemsetAsync(d_out, 0, (size_t)out_size * sizeof(float), stream);

  hipLaunchKernelGGL(cvt_features, dim3(2048), dim3(256), 0, stream, features, Fb);
  hipLaunchKernelGGL(transpose_w1, dim3(KDIM / 32, HID_ / 32), dim3(256), 0, stream, W1, BTm);
  hipLaunchKernelGGL(roi_pool, dim3(NROI * 49 / 4), dim3(256), 0, stream, Fb, rois, X);
  hipLaunchKernelGGL(gemm_h, dim3((NROI / BM) * (HID_ / BN)), dim3(256), 0, stream, X, BTm, b1, Hh);
  hipLaunchKernelGGL(heads_k, dim3(NROI / 2), dim3(256), 0, stream, Hh, Wc, bc, Wb, bb, logits, bbox);
  hipLaunchKernelGGL(loss_k, dim3(NROI / 256), dim3(256), 0, stream, logits, bbox, labels, tgt, (float*)d_out);
}

// Round 2
// 260.476 us; speedup vs baseline: 1.2334x; 1.2334x over previous
//
#include <hip/hip_runtime.h>

#define H_    200
#define W_    200
#define C_    256
#define NROI  4096
#define KDIM  12544   // 49*256
#define KHALF 6272    // KDIM/2
#define HID_  256
#define NCLS_ 21

typedef __bf16 bf16x8 __attribute__((ext_vector_type(8)));
typedef float  f32x4  __attribute__((ext_vector_type(4)));
typedef unsigned short u16x8 __attribute__((ext_vector_type(8)));

__device__ __forceinline__ unsigned short f2bf(float f) {
  unsigned u = __float_as_uint(f);
  return (unsigned short)((u + 0x7FFFu + ((u >> 16) & 1u)) >> 16);  // RNE, no NaN inputs
}
__device__ __forceinline__ float bf2f(unsigned short u) {
  return __uint_as_float(((unsigned)u) << 16);
}
__device__ __forceinline__ void gload16(const void* g, void* l) {
  __builtin_amdgcn_global_load_lds((const __attribute__((address_space(1))) unsigned int*)g,
                                   (__attribute__((address_space(3))) unsigned int*)l, 16, 0, 0);
}

// ---------------- features f32 -> bf16 ----------------
__global__ __launch_bounds__(256) void cvt_features(const float* __restrict__ F,
                                                    unsigned short* __restrict__ Fb) {
  const int n4 = (H_ * W_ * C_) / 4;
  for (int i = blockIdx.x * 256 + threadIdx.x; i < n4; i += gridDim.x * 256) {
    float4 v = ((const float4*)F)[i];
    ushort4 o;
    o.x = f2bf(v.x); o.y = f2bf(v.y); o.z = f2bf(v.z); o.w = f2bf(v.w);
    ((ushort4*)Fb)[i] = o;
  }
}

// ---------------- W1 (K x N) f32 -> BT (N x K) bf16 ----------------
__global__ __launch_bounds__(256) void transpose_w1(const float* __restrict__ W1,
                                                    unsigned short* __restrict__ BT) {
  __shared__ float tile[32][33];
  const int k0 = blockIdx.x * 32;   // 392
  const int n0 = blockIdx.y * 32;   // 8
  const int tx = threadIdx.x & 31;
  const int ty = threadIdx.x >> 5;  // 0..7
#pragma unroll
  for (int i = 0; i < 4; ++i)
    tile[ty + 8 * i][tx] = W1[(size_t)(k0 + ty + 8 * i) * HID_ + n0 + tx];
  __syncthreads();
#pragma unroll
  for (int i = 0; i < 4; ++i) {
    const int n = ty + 8 * i;
    BT[(size_t)(n0 + n) * KDIM + k0 + tx] = f2bf(tile[tx][n]);
  }
}

// ---------------- ROI max pool: X (NROI x KDIM) bf16, 16B/lane ----------------
__global__ __launch_bounds__(256) void roi_pool(const unsigned short* __restrict__ Fb,
                                                const float* __restrict__ rois,
                                                unsigned short* __restrict__ X) {
  const int task = blockIdx.x * 8 + (threadIdx.x >> 5);  // (roi, cell)
  const int ch8  = threadIdx.x & 31;                     // 8-channel group
  const int roi  = task / 49;
  const int cell = task - roi * 49;
  const int py = cell / 7;
  const int px = cell - py * 7;

  float4 r = ((const float4*)rois)[roi];
  const float y1 = fminf(r.x, r.z), y2 = fmaxf(r.x, r.z);
  const float x1 = fminf(r.y, r.w), x2 = fmaxf(r.y, r.w);
  const float dy = __fsub_rn(y2, y1), dx = __fsub_rn(x2, x1);

  int iy[2], ix[2];
#pragma unroll
  for (int g = 0; g < 2; ++g) {
    float tyv = __fdiv_rn(__fadd_rn((float)(2 * py + g), 0.5f), 14.0f);
    float txv = __fdiv_rn(__fadd_rn((float)(2 * px + g), 0.5f), 14.0f);
    float ys = __fadd_rn(y1, __fmul_rn(dy, tyv));
    float xs = __fadd_rn(x1, __fmul_rn(dx, txv));
    int yi = (int)rintf(__fmul_rn(ys, 199.0f));
    int xi = (int)rintf(__fmul_rn(xs, 199.0f));
    iy[g] = min(max(yi, 0), H_ - 1);
    ix[g] = min(max(xi, 0), W_ - 1);
  }

  const size_t co = (size_t)ch8 * 8;
  u16x8 a = *(const u16x8*)(Fb + ((size_t)(iy[0] * W_ + ix[0])) * C_ + co);
  u16x8 b = *(const u16x8*)(Fb + ((size_t)(iy[0] * W_ + ix[1])) * C_ + co);
  u16x8 c = *(const u16x8*)(Fb + ((size_t)(iy[1] * W_ + ix[0])) * C_ + co);
  u16x8 d = *(const u16x8*)(Fb + ((size_t)(iy[1] * W_ + ix[1])) * C_ + co);
  u16x8 o;
#pragma unroll
  for (int j = 0; j < 8; ++j) {
    float m = fmaxf(fmaxf(bf2f(a[j]), bf2f(b[j])), fmaxf(bf2f(c[j]), bf2f(d[j])));
    o[j] = (unsigned short)(__float_as_uint(m) >> 16);  // exact: max of bf16 values
  }
  *(u16x8*)(X + (size_t)roi * KDIM + cell * 256 + co) = o;
}

// ---------------- GEMM: partial H = X @ W1 over one K-half, bf16 MFMA ----------------
#define BM 64
#define BN 64
#define BK 64
#define NT (KHALF / BK)   // 98

__global__ __launch_bounds__(256) void gemm_h(const unsigned short* __restrict__ X,
                                              const unsigned short* __restrict__ BT,
                                              float* __restrict__ Hh0,
                                              float* __restrict__ Hh1) {
  __shared__ __align__(16) unsigned char As[2][BM * 128];  // 64 rows x 128B (swizzled)
  __shared__ __align__(16) unsigned char Bs[2][BN * 128];
  const int tid  = threadIdx.x;
  const int lane = tid & 63;
  const int w    = tid >> 6;   // wave 0..3

  // XCD co-location: blocks sharing (bm,half) have blockIdx == same (mod 8)
  const int b    = blockIdx.x;
  const int x8   = b & 7;
  const int bn   = (b >> 3) & 3;
  const int g    = (b >> 5) * 8 + x8;   // 0..127
  const int bm   = g >> 1;              // 0..63
  const int half = g & 1;

  // --- staging: linear LDS dest, inverse-swizzled global source ---
  const int srow  = lane >> 3;                          // 0..7
  const int sbyte = ((lane & 7) << 4) ^ (srow << 4);
  const size_t kbase = (size_t)half * KHALF + (sbyte >> 1);
  const unsigned short* gA0 = X  + (size_t)(bm * BM + w * 16 + srow) * KDIM + kbase;
  const unsigned short* gA1 = gA0 + (size_t)8 * KDIM;
  const unsigned short* gB0 = BT + (size_t)(bn * BN + w * 16 + srow) * KDIM + kbase;
  const unsigned short* gB1 = gB0 + (size_t)8 * KDIM;
  unsigned char* ldsA0[2] = { &As[0][(w * 16) * 128],     &As[1][(w * 16) * 128] };
  unsigned char* ldsA1[2] = { &As[0][(w * 16 + 8) * 128], &As[1][(w * 16 + 8) * 128] };
  unsigned char* ldsB0[2] = { &Bs[0][(w * 16) * 128],     &Bs[1][(w * 16) * 128] };
  unsigned char* ldsB1[2] = { &Bs[0][(w * 16 + 8) * 128], &Bs[1][(w * 16 + 8) * 128] };

  // --- LDS fragment-read offsets (swizzled) ---
  const int arow  = w * 16 + (lane & 15);
  const int kbyte = (lane >> 4) << 4;
  int aoff[2], boff[2][4];
#pragma unroll
  for (int kf = 0; kf < 2; ++kf) {
    const int kb = kf * 64 + kbyte;
    aoff[kf] = arow * 128 + (kb ^ ((arow & 7) << 4));
#pragma unroll
    for (int n = 0; n < 4; ++n) {
      const int brow = n * 16 + (lane & 15);
      boff[kf][n] = brow * 128 + (kb ^ ((brow & 7) << 4));
    }
  }

  f32x4 acc[4] = {};

  gload16(gA0, ldsA0[0]);
  gload16(gA1, ldsA1[0]);
  gload16(gB0, ldsB0[0]);
  gload16(gB1, ldsB1[0]);

  for (int t = 0; t < NT; ++t) {
    const int cur = t & 1;
    __syncthreads();
    if (t + 1 < NT) {
      const int nx = cur ^ 1;
      const size_t koff = (size_t)(t + 1) * BK;
      gload16(gA0 + koff, ldsA0[nx]);
      gload16(gA1 + koff, ldsA1[nx]);
      gload16(gB0 + koff, ldsB0[nx]);
      gload16(gB1 + koff, ldsB1[nx]);
    }
    const unsigned char* Ab = As[cur];
    const unsigned char* Bb = Bs[cur];
#pragma unroll
    for (int kf = 0; kf < 2; ++kf) {
      bf16x8 af = *(const bf16x8*)(Ab + aoff[kf]);
#pragma unroll
      for (int n = 0; n < 4; ++n) {
        bf16x8 bf = *(const bf16x8*)(Bb + boff[kf][n]);
        acc[n] = __builtin_amdgcn_mfma_f32_16x16x32_bf16(af, bf, acc[n], 0, 0, 0);
      }
    }
  }

  float* Hout = half ? Hh1 : Hh0;
  const int orow = bm * BM + w * 16 + ((lane >> 4) << 2);
#pragma unroll
  for (int n = 0; n < 4; ++n) {
    const int col = bn * BN + n * 16 + (lane & 15);
#pragma unroll
    for (int j = 0; j < 4; ++j)
      Hout[(size_t)(orow + j) * HID_ + col] = acc[n][j];
  }
}

// ---------------- hfin: H = relu(Hh0 + Hh1 + b1), in place into Hh0 ----------------
__global__ __launch_bounds__(256) void hfin(float* __restrict__ Hh0,
                                            const float* __restrict__ Hh1,
                                            const float* __restrict__ b1) {
  const int i = blockIdx.x * 256 + threadIdx.x;   // over NROI*HID_/4
  float4 a = ((const float4*)Hh0)[i];
  float4 b = ((const float4*)Hh1)[i];
  float4 c = ((const float4*)b1)[i & 63];
  float4 o;
  o.x = fmaxf(a.x + b.x + c.x, 0.f);
  o.y = fmaxf(a.y + b.y + c.y, 0.f);
  o.z = fmaxf(a.z + b.z + c.z, 0.f);
  o.w = fmaxf(a.w + b.w + c.w, 0.f);
  ((float4*)Hh0)[i] = o;
}

// ---------------- heads: logits (NROI x 21), bbox (NROI x 84) ----------------
__global__ __launch_bounds__(256) void heads_k(const float* __restrict__ Hh,
                                               const float* __restrict__ Wc,
                                               const float* __restrict__ bc,
                                               const float* __restrict__ Wb,
                                               const float* __restrict__ bb,
                                               float* __restrict__ logits,
                                               float* __restrict__ bbox) {
  const int t = threadIdx.x;
  const int roi = blockIdx.x * 2 + (t >> 7);
  const int o = t & 127;
  if (o >= 105) return;
  const float* h = Hh + (size_t)roi * HID_;
  const float* wp;
  int stride;
  float bias;
  if (o < 21) { wp = Wc + o;        stride = NCLS_;     bias = bc[o]; }
  else        { wp = Wb + (o - 21); stride = NCLS_ * 4; bias = bb[o - 21]; }
  float a0 = 0.f, a1 = 0.f, a2 = 0.f, a3 = 0.f;
#pragma unroll 4
  for (int k = 0; k < HID_; k += 4) {
    a0 = fmaf(h[k],     wp[(size_t)k * stride],           a0);
    a1 = fmaf(h[k + 1], wp[(size_t)(k + 1) * stride],     a1);
    a2 = fmaf(h[k + 2], wp[(size_t)(k + 2) * stride],     a2);
    a3 = fmaf(h[k + 3], wp[(size_t)(k + 3) * stride],     a3);
  }
  const float acc = bias + ((a0 + a1) + (a2 + a3));
  if (o < 21) logits[(size_t)roi * NCLS_ + o] = acc;
  else        bbox[(size_t)roi * 84 + (o - 21)] = acc;
}

// ---------------- per-ROI loss + reduction ----------------
__global__ __launch_bounds__(256) void loss_k(const float* __restrict__ logits,
                                              const float* __restrict__ bbox,
                                              const int* __restrict__ labels,
                                              const float* __restrict__ tgt,
                                              float* __restrict__ out) {
  const int roi = blockIdx.x * 256 + threadIdx.x;
  const float* lg = logits + (size_t)roi * NCLS_;
  float m = lg[0];
#pragma unroll
  for (int i = 1; i < NCLS_; ++i) m = fmaxf(m, lg[i]);
  float s = 0.f;
#pragma unroll
  for (int i = 0; i < NCLS_; ++i) s += expf(lg[i] - m);
  const float lse = m + logf(s);
  const int lab = labels[roi];
  float contrib = lse - lg[lab];
#pragma unroll
  for (int j = 0; j < 4; ++j) {
    float d = bbox[(size_t)roi * 84 + lab * 4 + j] - tgt[roi * 4 + j];
    float ad = fabsf(d);
    contrib += (ad < 1.f) ? 0.5f * d * d : ad - 0.5f;
  }
  contrib *= (1.0f / NROI);
#pragma unroll
  for (int off = 32; off > 0; off >>= 1) contrib += __shfl_down(contrib, off);
  __shared__ float wsum[4];
  const int lane = threadIdx.x & 63, wv = threadIdx.x >> 6;
  if (lane == 0) wsum[wv] = contrib;
  __syncthreads();
  if (threadIdx.x == 0) atomicAdd(out, wsum[0] + wsum[1] + wsum[2] + wsum[3]);
}

extern "C" void kernel_launch(void* const* d_in, const int* in_sizes, int n_in,
                              void* d_out, int out_size, void* d_ws, size_t ws_size,
                              hipStream_t stream) {
  const float* features = (const float*)d_in[0];
  const float* rois     = (const float*)d_in[1];
  const int*   labels   = (const int*)d_in[2];
  const float* tgt      = (const float*)d_in[3];
  const float* W1       = (const float*)d_in[4];
  const float* b1       = (const float*)d_in[5];
  const float* Wc       = (const float*)d_in[6];
  const float* bc       = (const float*)d_in[7];
  const float* Wb       = (const float*)d_in[8];
  const float* bb       = (const float*)d_in[9];

  char* ws = (char*)d_ws;
  unsigned short* X      = (unsigned short*)(ws);                 // 102,760,448 B
  unsigned short* BTm    = (unsigned short*)(ws + 102760448);     // 6,422,528 B
  // Fb region (20,480,000 B) is dead after roi_pool; overlay GEMM outputs there.
  unsigned short* Fb     = (unsigned short*)(ws + 109182976);
  float*          Hh0    = (float*)(ws + 109182976);              // 4,194,304 B
  float*          Hh1    = (float*)(ws + 113377280);              // 4,194,304 B
  float*          logits = (float*)(ws + 117571584);              // 344,064 B
  float*          bbox   = (float*)(ws + 117915648);              // 1,376,256 B

  hipMemsetAsync(d_out, 0, (size_t)out_size * sizeof(float), stream);

  hipLaunchKernelGGL(cvt_features, dim3(2048), dim3(256), 0, stream, features, Fb);
  hipLaunchKernelGGL(transpose_w1, dim3(KDIM / 32, HID_ / 32), dim3(256), 0, stream, W1, BTm);
  hipLaunchKernelGGL(roi_pool, dim3(NROI * 49 / 8), dim3(256), 0, stream, Fb, rois, X);
  hipLaunchKernelGGL(gemm_h, dim3(512), dim3(256), 0, stream, X, BTm, Hh0, Hh1);
  hipLaunchKernelGGL(hfin, dim3(NROI * HID_ / 4 / 256), dim3(256), 0, stream, Hh0, Hh1, b1);
  hipLaunchKernelGGL(heads_k, dim3(NROI / 2), dim3(256), 0, stream, Hh0, Wc, bc, Wb, bb, logits, bbox);
  hipLaunchKernelGGL(loss_k, dim3(NROI / 256), dim3(256), 0, stream, logits, bbox, labels, tgt, (float*)d_out);
}

// Round 3
// 218.840 us; speedup vs baseline: 1.4681x; 1.1903x over previous
//
#include <hip/hip_runtime.h>

#define H_    200
#define W_    200
#define C_    256
#define NROI  4096
#define KDIM  12544   // 49*256
#define HID_  256
#define NCLS_ 21
#define NTASK (NROI * 49)
#define NSPLIT 8
#define NHEAD 112     // 21 + 84, padded to 7*16

typedef __bf16 bf16x8 __attribute__((ext_vector_type(8)));
typedef float  f32x4  __attribute__((ext_vector_type(4)));
typedef unsigned short u16x8 __attribute__((ext_vector_type(8)));

__device__ __forceinline__ unsigned short f2bf(float f) {
  unsigned u = __float_as_uint(f);
  return (unsigned short)((u + 0x7FFFu + ((u >> 16) & 1u)) >> 16);  // RNE, no NaN inputs
}
__device__ __forceinline__ float bf2f(unsigned short u) {
  return __uint_as_float(((unsigned)u) << 16);
}
__device__ __forceinline__ void gload16(const void* g, void* l) {
  __builtin_amdgcn_global_load_lds((const __attribute__((address_space(1))) unsigned int*)g,
                                   (__attribute__((address_space(3))) unsigned int*)l, 16, 0, 0);
}

// ---------------- features f32 -> bf16 ----------------
__global__ __launch_bounds__(256) void cvt_features(const float* __restrict__ F,
                                                    unsigned short* __restrict__ Fb) {
  const int n4 = (H_ * W_ * C_) / 4;
  for (int i = blockIdx.x * 256 + threadIdx.x; i < n4; i += gridDim.x * 256) {
    float4 v = ((const float4*)F)[i];
    ushort4 o;
    o.x = f2bf(v.x); o.y = f2bf(v.y); o.z = f2bf(v.z); o.w = f2bf(v.w);
    ((ushort4*)Fb)[i] = o;
  }
}

// ---------------- W1 (K x N) f32 -> BT (N x K) bf16 ----------------
__global__ __launch_bounds__(256) void transpose_w1(const float* __restrict__ W1,
                                                    unsigned short* __restrict__ BT) {
  __shared__ float tile[32][33];
  const int k0 = blockIdx.x * 32;   // 392
  const int n0 = blockIdx.y * 32;   // 8
  const int tx = threadIdx.x & 31;
  const int ty = threadIdx.x >> 5;  // 0..7
#pragma unroll
  for (int i = 0; i < 4; ++i)
    tile[ty + 8 * i][tx] = W1[(size_t)(k0 + ty + 8 * i) * HID_ + n0 + tx];
  __syncthreads();
#pragma unroll
  for (int i = 0; i < 4; ++i) {
    const int n = ty + 8 * i;
    BT[(size_t)(n0 + n) * KDIM + k0 + tx] = f2bf(tile[tx][n]);
  }
}

// ---------------- heads weights: WT[112][256] bf16 + bias[112] ----------------
__global__ __launch_bounds__(256) void wprep(const float* __restrict__ Wc,
                                             const float* __restrict__ bc,
                                             const float* __restrict__ Wb,
                                             const float* __restrict__ bb,
                                             unsigned short* __restrict__ WT,
                                             float* __restrict__ Wbias) {
  const int n = blockIdx.x;       // 0..111
  const int k = threadIdx.x;      // 0..255
  float v = 0.f;
  if (n < 21)       v = Wc[(size_t)k * NCLS_ + n];
  else if (n < 105) v = Wb[(size_t)k * (NCLS_ * 4) + (n - 21)];
  WT[(size_t)n * HID_ + k] = f2bf(v);
  if (k == 0) Wbias[n] = (n < 21) ? bc[n] : ((n < 105) ? bb[n - 21] : 0.f);
}

// ---------------- per-task gather bases: short4{iy0,iy1,ix0,ix1} ----------------
__global__ __launch_bounds__(256) void prep_bases(const float* __restrict__ rois,
                                                  short4* __restrict__ Bases) {
  const int task = blockIdx.x * 256 + threadIdx.x;
  const int roi  = task / 49;
  const int cell = task - roi * 49;
  const int py = cell / 7;
  const int px = cell - py * 7;

  float4 r = ((const float4*)rois)[roi];
  const float y1 = fminf(r.x, r.z), y2 = fmaxf(r.x, r.z);
  const float x1 = fminf(r.y, r.w), x2 = fmaxf(r.y, r.w);
  const float dy = __fsub_rn(y2, y1), dx = __fsub_rn(x2, x1);

  short v[4];
#pragma unroll
  for (int g = 0; g < 2; ++g) {
    float tyv = __fdiv_rn(__fadd_rn((float)(2 * py + g), 0.5f), 14.0f);
    float txv = __fdiv_rn(__fadd_rn((float)(2 * px + g), 0.5f), 14.0f);
    float ys = __fadd_rn(y1, __fmul_rn(dy, tyv));
    float xs = __fadd_rn(x1, __fmul_rn(dx, txv));
    int yi = (int)rintf(__fmul_rn(ys, 199.0f));
    int xi = (int)rintf(__fmul_rn(xs, 199.0f));
    v[g]     = (short)min(max(yi, 0), H_ - 1);
    v[2 + g] = (short)min(max(xi, 0), W_ - 1);
  }
  Bases[task] = make_short4(v[0], v[1], v[2], v[3]);
}

// ---------------- ROI max pool: X (NROI x KDIM) bf16, slim ----------------
__global__ __launch_bounds__(256) void roi_pool(const unsigned short* __restrict__ Fb,
                                                const short4* __restrict__ Bases,
                                                unsigned short* __restrict__ X) {
  const int task = blockIdx.x * 8 + (threadIdx.x >> 5);
  const int ch8  = threadIdx.x & 31;
  const short4 bs = Bases[task];
  const int iy0 = bs.x, iy1 = bs.y, ix0 = bs.z, ix1 = bs.w;

  const size_t co = (size_t)ch8 * 8;
  u16x8 a = *(const u16x8*)(Fb + ((size_t)(iy0 * W_ + ix0)) * C_ + co);
  u16x8 b = *(const u16x8*)(Fb + ((size_t)(iy0 * W_ + ix1)) * C_ + co);
  u16x8 c = *(const u16x8*)(Fb + ((size_t)(iy1 * W_ + ix0)) * C_ + co);
  u16x8 d = *(const u16x8*)(Fb + ((size_t)(iy1 * W_ + ix1)) * C_ + co);
  u16x8 o;
#pragma unroll
  for (int j = 0; j < 8; ++j) {
    float m = fmaxf(fmaxf(bf2f(a[j]), bf2f(b[j])), fmaxf(bf2f(c[j]), bf2f(d[j])));
    o[j] = (unsigned short)(__float_as_uint(m) >> 16);  // exact: max of bf16
  }
  *(u16x8*)(X + (size_t)task * 256 + co) = o;   // task*256 == roi*KDIM + cell*256
}

// ---------------- GEMM: partial H (bf16) = X @ W1 over K-split, 128x128 ----------------
__global__ __launch_bounds__(256) void gemm_h(const unsigned short* __restrict__ X,
                                              const unsigned short* __restrict__ BT,
                                              unsigned short* __restrict__ Hp) {
  __shared__ __align__(16) unsigned char As[2][128 * 128];
  __shared__ __align__(16) unsigned char Bs[2][128 * 128];
  const int tid  = threadIdx.x;
  const int lane = tid & 63;
  const int w    = tid >> 6;
  const int wr   = w >> 1, wc = w & 1;   // 2x2 wave grid, each 64x64

  // XCD co-location: both bn-blocks of a (bm,split) key share blockIdx mod 8
  const int b     = blockIdx.x;
  const int x8    = b & 7;
  const int r     = b >> 3;
  const int bn    = r & 1;
  const int key   = (r >> 1) * 8 + x8;   // 0..255
  const int bm    = key >> 3;            // 0..31
  const int split = key & 7;
  const int t0 = (49 * split) >> 1;
  const int nt = ((49 * (split + 1)) >> 1) - t0;   // 24 or 25

  // --- staging: linear LDS dest, inverse-swizzled global source ---
  const int srow  = lane >> 3;
  const int sbyte = ((lane & 7) << 4) ^ (srow << 4);
  const size_t kbase = (size_t)t0 * 64 + (sbyte >> 1);
  const int rofs[4] = {0, 8, 64, 72};
  const unsigned short* gA[4];
  const unsigned short* gB[4];
#pragma unroll
  for (int i = 0; i < 4; ++i) {
    const int row = w * 16 + rofs[i] + srow;
    gA[i] = X  + (size_t)(bm * 128 + row) * KDIM + kbase;
    gB[i] = BT + (size_t)(bn * 128 + row) * KDIM + kbase;
  }

  // --- LDS fragment-read offsets (swizzled) ---
  int aoff[4][2], boff[4][2];
#pragma unroll
  for (int m = 0; m < 4; ++m) {
#pragma unroll
    for (int kf = 0; kf < 2; ++kf) {
      const int kb = kf * 64 + ((lane >> 4) << 4);
      const int arow = wr * 64 + m * 16 + (lane & 15);
      const int brow = wc * 64 + m * 16 + (lane & 15);
      aoff[m][kf] = arow * 128 + (kb ^ ((arow & 7) << 4));
      boff[m][kf] = brow * 128 + (kb ^ ((brow & 7) << 4));
    }
  }

  f32x4 acc[4][4] = {};

#pragma unroll
  for (int i = 0; i < 4; ++i) {
    gload16(gA[i], &As[0][(w * 16 + rofs[i]) * 128]);
    gload16(gB[i], &Bs[0][(w * 16 + rofs[i]) * 128]);
  }

  for (int t = 0; t < nt; ++t) {
    const int cur = t & 1;
    __syncthreads();
    if (t + 1 < nt) {
      const int nx = cur ^ 1;
      const size_t koff = (size_t)(t + 1) * 64;
#pragma unroll
      for (int i = 0; i < 4; ++i) {
        gload16(gA[i] + koff, &As[nx][(w * 16 + rofs[i]) * 128]);
        gload16(gB[i] + koff, &Bs[nx][(w * 16 + rofs[i]) * 128]);
      }
    }
    const unsigned char* Ab = As[cur];
    const unsigned char* Bb = Bs[cur];
#pragma unroll
    for (int kf = 0; kf < 2; ++kf) {
      bf16x8 af[4], bf[4];
#pragma unroll
      for (int m = 0; m < 4; ++m) af[m] = *(const bf16x8*)(Ab + aoff[m][kf]);
#pragma unroll
      for (int n = 0; n < 4; ++n) bf[n] = *(const bf16x8*)(Bb + boff[n][kf]);
#pragma unroll
      for (int m = 0; m < 4; ++m)
#pragma unroll
        for (int n = 0; n < 4; ++n)
          acc[m][n] = __builtin_amdgcn_mfma_f32_16x16x32_bf16(af[m], bf[n], acc[m][n], 0, 0, 0);
    }
  }

  // epilogue: bf16 partials, Hp[split][4096][256]
  const int growb = bm * 128 + wr * 64 + ((lane >> 4) << 2);
  const int gcolb = bn * 128 + wc * 64 + (lane & 15);
  unsigned short* Ho = Hp + (size_t)split * NROI * HID_;
#pragma unroll
  for (int m = 0; m < 4; ++m)
#pragma unroll
    for (int n = 0; n < 4; ++n)
#pragma unroll
      for (int j = 0; j < 4; ++j)
        Ho[(size_t)(growb + m * 16 + j) * HID_ + gcolb + n * 16] = f2bf(acc[m][n][j]);
}

// ---------------- hfin: Hb = bf16(relu(sum_s Hp[s] + b1)) ----------------
__global__ __launch_bounds__(256) void hfin(const unsigned short* __restrict__ Hp,
                                            const float* __restrict__ b1,
                                            unsigned short* __restrict__ Hb) {
  const int i = blockIdx.x * 256 + threadIdx.x;   // over NROI*HID_/8
  const size_t base = (size_t)i * 8;
  const int c8 = (i & 31) * 8;
  float s[8];
#pragma unroll
  for (int j = 0; j < 8; ++j) s[j] = b1[c8 + j];
#pragma unroll
  for (int sp = 0; sp < NSPLIT; ++sp) {
    u16x8 v = *(const u16x8*)(Hp + (size_t)sp * NROI * HID_ + base);
#pragma unroll
    for (int j = 0; j < 8; ++j) s[j] += bf2f(v[j]);
  }
  u16x8 o;
#pragma unroll
  for (int j = 0; j < 8; ++j) o[j] = f2bf(fmaxf(s[j], 0.f));
  *(u16x8*)(Hb + base) = o;
}

// ---------------- heads: O[4096][112] = Hb @ WT^T + bias, MFMA direct-from-global ----------------
__global__ __launch_bounds__(256) void heads_k(const unsigned short* __restrict__ Hb,
                                               const unsigned short* __restrict__ WT,
                                               const float* __restrict__ Wbias,
                                               float* __restrict__ O) {
  const int lane = threadIdx.x & 63;
  const int w    = threadIdx.x >> 6;
  const int roiBase = blockIdx.x * 64 + w * 16;
  const int arow = roiBase + (lane & 15);
  const int koff = (lane >> 4) << 3;

  f32x4 acc[7] = {};
#pragma unroll
  for (int k0 = 0; k0 < HID_; k0 += 32) {
    bf16x8 av = *(const bf16x8*)(Hb + (size_t)arow * HID_ + k0 + koff);
#pragma unroll
    for (int n = 0; n < 7; ++n) {
      bf16x8 bv = *(const bf16x8*)(WT + (size_t)(n * 16 + (lane & 15)) * HID_ + k0 + koff);
      acc[n] = __builtin_amdgcn_mfma_f32_16x16x32_bf16(av, bv, acc[n], 0, 0, 0);
    }
  }
  const int orow = roiBase + ((lane >> 4) << 2);
#pragma unroll
  for (int n = 0; n < 7; ++n) {
    const int col = n * 16 + (lane & 15);
    const float bv = Wbias[col];
#pragma unroll
    for (int j = 0; j < 4; ++j)
      O[(size_t)(orow + j) * NHEAD + col] = acc[n][j] + bv;
  }
}

// ---------------- per-ROI loss + reduction ----------------
__global__ __launch_bounds__(256) void loss_k(const float* __restrict__ O,
                                              const int* __restrict__ labels,
                                              const float* __restrict__ tgt,
                                              float* __restrict__ out) {
  const int roi = blockIdx.x * 256 + threadIdx.x;
  const float* lg = O + (size_t)roi * NHEAD;
  float m = lg[0];
#pragma unroll
  for (int i = 1; i < NCLS_; ++i) m = fmaxf(m, lg[i]);
  float s = 0.f;
#pragma unroll
  for (int i = 0; i < NCLS_; ++i) s += expf(lg[i] - m);
  const float lse = m + logf(s);
  const int lab = labels[roi];
  float contrib = lse - lg[lab];
#pragma unroll
  for (int j = 0; j < 4; ++j) {
    float d = lg[NCLS_ + lab * 4 + j] - tgt[roi * 4 + j];
    float ad = fabsf(d);
    contrib += (ad < 1.f) ? 0.5f * d * d : ad - 0.5f;
  }
  contrib *= (1.0f / NROI);
#pragma unroll
  for (int off = 32; off > 0; off >>= 1) contrib += __shfl_down(contrib, off);
  __shared__ float wsum[4];
  const int lane = threadIdx.x & 63, wv = threadIdx.x >> 6;
  if (lane == 0) wsum[wv] = contrib;
  __syncthreads();
  if (threadIdx.x == 0) atomicAdd(out, wsum[0] + wsum[1] + wsum[2] + wsum[3]);
}

extern "C" void kernel_launch(void* const* d_in, const int* in_sizes, int n_in,
                              void* d_out, int out_size, void* d_ws, size_t ws_size,
                              hipStream_t stream) {
  const float* features = (const float*)d_in[0];
  const float* rois     = (const float*)d_in[1];
  const int*   labels   = (const int*)d_in[2];
  const float* tgt      = (const float*)d_in[3];
  const float* W1       = (const float*)d_in[4];
  const float* b1       = (const float*)d_in[5];
  const float* Wc       = (const float*)d_in[6];
  const float* bc       = (const float*)d_in[7];
  const float* Wb       = (const float*)d_in[8];
  const float* bb       = (const float*)d_in[9];

  char* ws = (char*)d_ws;
  unsigned short* X      = (unsigned short*)(ws);                 // 102,760,448
  unsigned short* BTm    = (unsigned short*)(ws + 102760448);     // 6,422,528
  unsigned short* Fb     = (unsigned short*)(ws + 109182976);     // 20,480,000 (dead after pool)
  unsigned short* Hp     = (unsigned short*)(ws + 109182976);     // 16,777,216 (overlays Fb)
  short4*         Bases  = (short4*)(ws + 129662976);             // 1,605,632
  unsigned short* Hb     = (unsigned short*)(ws + 131268608);     // 2,097,152
  unsigned short* WT     = (unsigned short*)(ws + 133365760);     // 57,344
  float*          Wbias  = (float*)(ws + 133423104);              // 512
  float*          O      = (float*)(ws + 133423616);              // 1,835,008 -> end 135,258,624

  hipMemsetAsync(d_out, 0, (size_t)out_size * sizeof(float), stream);

  hipLaunchKernelGGL(cvt_features, dim3(2048), dim3(256), 0, stream, features, Fb);
  hipLaunchKernelGGL(transpose_w1, dim3(KDIM / 32, HID_ / 32), dim3(256), 0, stream, W1, BTm);
  hipLaunchKernelGGL(wprep, dim3(NHEAD), dim3(256), 0, stream, Wc, bc, Wb, bb, WT, Wbias);
  hipLaunchKernelGGL(prep_bases, dim3(NTASK / 256), dim3(256), 0, stream, rois, Bases);
  hipLaunchKernelGGL(roi_pool, dim3(NTASK / 8), dim3(256), 0, stream, Fb, Bases, X);
  hipLaunchKernelGGL(gemm_h, dim3(512), dim3(256), 0, stream, X, BTm, Hp);
  hipLaunchKernelGGL(hfin, dim3(NROI * HID_ / 8 / 256), dim3(256), 0, stream, Hp, b1, Hb);
  hipLaunchKernelGGL(heads_k, dim3(NROI / 64), dim3(256), 0, stream, Hb, WT, Wbias, O);
  hipLaunchKernelGGL(loss_k, dim3(NROI / 256), dim3(256), 0, stream, O, labels, tgt, (float*)d_out);
}